// Round 1
// baseline (2114.008 us; speedup 1.0000x reference)
//
#include <hip/hip_runtime.h>
#include <math.h>

#define NN 100000
#define D 64
#define S 8
#define WSTRIDE 68   // LDS row stride: 68*4B = 272B, 16B-aligned rows, bank-spread

// broadcast x from lane l (l compile-time const after unroll) -> uniform SGPR value
__device__ __forceinline__ float bc(float x, int l) {
  return __int_as_float(__builtin_amdgcn_readlane(__float_as_int(x), l));
}

__device__ __forceinline__ float wred(float x) {
  x += __shfl_xor(x, 1, 64);
  x += __shfl_xor(x, 2, 64);
  x += __shfl_xor(x, 4, 64);
  x += __shfl_xor(x, 8, 64);
  x += __shfl_xor(x, 16, 64);
  x += __shfl_xor(x, 32, 64);
  return x;
}

// out[lane] = b + sum_k W[lane][k] * x[k], W staged in LDS with stride WSTRIDE.
__device__ __forceinline__ float matvec_row(const float* Wlds, float x, float b, int lane) {
  float a0 = 0.f, a1 = 0.f, a2 = 0.f, a3 = 0.f;
  const float* wr = Wlds + lane * WSTRIDE;
#pragma unroll
  for (int k4 = 0; k4 < 16; k4++) {
    float4 w = *(const float4*)(wr + 4 * k4);
    a0 = fmaf(w.x, bc(x, 4 * k4 + 0), a0);
    a1 = fmaf(w.y, bc(x, 4 * k4 + 1), a1);
    a2 = fmaf(w.z, bc(x, 4 * k4 + 2), a2);
    a3 = fmaf(w.w, bc(x, 4 * k4 + 3), a3);
  }
  return b + ((a0 + a1) + (a2 + a3));
}

// One attention branch for one node (whole wave). lane owns dim `lane`.
__device__ __forceinline__ float branch_eval(
    const float* __restrict__ table, const int* idx, const float* Wlds,
    float b_lane, float href, float att_lo, float att_hi, int lane) {
  float refp = matvec_row(Wlds, href, b_lane, lane);
  float v[S];
#pragma unroll
  for (int s = 0; s < S; s++) v[s] = table[idx[s] * D + lane];
  float dot_lo = wred(refp * att_lo);
  float asum_r = wred(fabsf(refp));
  float sc[S];
#pragma unroll
  for (int s = 0; s < S; s++) {
    float bsum = wred(fabsf(v[s]));
    float bdot = wred(v[s] * att_hi);
    float t = (dot_lo + bdot) / fmaxf(asum_r + bsum, 1e-12f);
    sc[s] = (t >= 0.f) ? t : 0.01f * t;  // leaky_relu(0.01)
  }
  float m = sc[0];
#pragma unroll
  for (int s = 1; s < S; s++) m = fmaxf(m, sc[s]);
  float den = 0.f, wexp[S];
#pragma unroll
  for (int s = 0; s < S; s++) { wexp[s] = expf(sc[s] - m); den += wexp[s]; }
  float inv = 1.f / den;
  float e = 0.f;
#pragma unroll
  for (int s = 0; s < S; s++) e = fmaf(wexp[s] * inv, v[s], e);
  return e;
}

__global__ void k_zero(float* p) { p[blockIdx.x * 256 + threadIdx.x] = 0.f; }

__global__ void __launch_bounds__(256) k_relation(
    const int* __restrict__ nei,
    const float* __restrict__ table, const float* __restrict__ rtable,
    const float* __restrict__ ref, const float* __restrict__ rref,
    const float* __restrict__ att, const float* __restrict__ att2,
    const float* __restrict__ Wr, const float* __restrict__ br,
    const float* __restrict__ Wr2, const float* __restrict__ br2,
    const float* __restrict__ aggW, const float* __restrict__ aggb,
    float* __restrict__ outA, float* __restrict__ outR,
    float* __restrict__ sumA, float* __restrict__ sumR) {
  __shared__ float WrS[D * WSTRIDE], Wr2S[D * WSTRIDE], aggWS[D * WSTRIDE];
  int tid = threadIdx.x;
  for (int i = tid; i < D * 16; i += 256) {
    int row = i >> 4, c4 = i & 15;
    ((float4*)(WrS + row * WSTRIDE))[c4]   = ((const float4*)Wr)[i];
    ((float4*)(Wr2S + row * WSTRIDE))[c4]  = ((const float4*)Wr2)[i];
    ((float4*)(aggWS + row * WSTRIDE))[c4] = ((const float4*)aggW)[i];
  }
  __syncthreads();
  int lane = tid & 63;
  int wid = tid >> 6;
  float attA_lo = att[lane],  attA_hi = att[D + lane];
  float attR_lo = att2[lane], attR_hi = att2[D + lane];
  float br_l = br[lane], br2_l = br2[lane], aggb_l = aggb[lane];
  float accA = 0.f, accR = 0.f;
  int nwaves = gridDim.x * 4;
  for (int n = blockIdx.x * 4 + wid; n < NN; n += nwaves) {
    int idx[S];
#pragma unroll
    for (int s = 0; s < S; s++) idx[s] = nei[n * S + s];
    float h  = ref[n * D + lane];
    float rr = rref[n * D + lane];
    float eA = branch_eval(table,  idx, WrS,  br_l,  h,  attA_lo, attA_hi, lane);
    float eR = branch_eval(rtable, idx, Wr2S, br2_l, rr, attR_lo, attR_hi, lane);
    outA[n * D + lane] = eA;
    outR[n * D + lane] = eR;
    accA += tanhf(matvec_row(aggWS, eA, aggb_l, lane));
    accR += tanhf(matvec_row(aggWS, eR, aggb_l, lane));
  }
  atomicAdd(&sumA[lane], accA);
  atomicAdd(&sumR[lane], accR);
}

__global__ void k_intra_beta(const float* __restrict__ sums,
                             const float* __restrict__ aggatt0,
                             const float* __restrict__ aggatt1,
                             float* __restrict__ betas) {
  int lane = threadIdx.x;  // 64 threads = 1 wave
  float invN = 1.f / (float)NN;
#pragma unroll
  for (int r = 0; r < 2; r++) {
    const float* aggatt = r ? aggatt1 : aggatt0;
    float ga = wred(aggatt[lane] * sums[r * 128 + lane] * invN);
    float gb = wred(aggatt[lane] * sums[r * 128 + 64 + lane] * invN);
    float m = fmaxf(ga, gb);
    float ea = expf(ga - m), eb = expf(gb - m);
    if (lane == 0) {
      betas[2 * r]     = ea / (ea + eb);
      betas[2 * r + 1] = eb / (ea + eb);
    }
  }
}

__global__ void __launch_bounds__(256) k_mix(
    float* pA0, const float* __restrict__ pR0,
    float* pA1, const float* __restrict__ pR1,
    const float* __restrict__ target,
    const float* __restrict__ interW, const float* __restrict__ interb,
    const float* __restrict__ betas,
    float* __restrict__ S0, float* __restrict__ S1, float* __restrict__ S2) {
  __shared__ float WS[D * WSTRIDE];
  int tid = threadIdx.x;
  for (int i = tid; i < D * 16; i += 256) {
    int row = i >> 4, c4 = i & 15;
    ((float4*)(WS + row * WSTRIDE))[c4] = ((const float4*)interW)[i];
  }
  __syncthreads();
  int lane = tid & 63, wid = tid >> 6;
  float ib_l = interb[lane];
  float ba0 = betas[0], bb0 = betas[1], ba1 = betas[2], bb1 = betas[3];
  float a0s = 0.f, a1s = 0.f, a2s = 0.f;
  int nwaves = gridDim.x * 4;
  for (int n = blockIdx.x * 4 + wid; n < NN; n += nwaves) {
    float eA0 = pA0[n * D + lane], eR0 = pR0[n * D + lane];
    float eA1 = pA1[n * D + lane], eR1 = pR1[n * D + lane];
    float t = target[n * D + lane];
    float x0 = ba0 * eA0 + bb0 * eR0;
    float x1 = ba1 * eA1 + bb1 * eR1;
    float e0 = (x0 > 0.f) ? x0 : expm1f(x0);  // elu
    float e1 = (x1 > 0.f) ? x1 : expm1f(x1);
    pA0[n * D + lane] = e0;
    pA1[n * D + lane] = e1;
    a0s += tanhf(matvec_row(WS, e0, ib_l, lane));
    a1s += tanhf(matvec_row(WS, e1, ib_l, lane));
    a2s += tanhf(matvec_row(WS, t,  ib_l, lane));
  }
  atomicAdd(&S0[lane], a0s);
  atomicAdd(&S1[lane], a1s);
  atomicAdd(&S2[lane], a2s);
}

__global__ void k_final_beta(const float* __restrict__ Ssum,
                             const float* __restrict__ interatt,
                             float* __restrict__ fbetas) {
  int lane = threadIdx.x;  // 64 threads
  float invN = 1.f / (float)NN;
  float ia = interatt[lane];
  float d0 = wred(ia * Ssum[lane] * invN);
  float d1 = wred(ia * Ssum[64 + lane] * invN);
  float d2 = wred(ia * Ssum[128 + lane] * invN);
  float m = fmaxf(fmaxf(d0, d1), d2);
  float e0 = expf(d0 - m), e1 = expf(d1 - m), e2 = expf(d2 - m);
  float inv = 1.f / (e0 + e1 + e2);
  if (lane == 0) { fbetas[0] = e0 * inv; fbetas[1] = e1 * inv; fbetas[2] = e2 * inv; }
}

__global__ void __launch_bounds__(256) k_out(
    const float4* __restrict__ E0, const float4* __restrict__ E1,
    const float4* __restrict__ T, const float* __restrict__ fb,
    float4* __restrict__ out) {
  float b0 = fb[0], b1 = fb[1], b2 = fb[2];
  int total = NN * D / 4;
  for (int i = blockIdx.x * blockDim.x + threadIdx.x; i < total; i += gridDim.x * blockDim.x) {
    float4 a = E0[i], b = E1[i], c = T[i];
    float4 o;
    o.x = b0 * a.x + b1 * b.x + b2 * c.x;
    o.y = b0 * a.y + b1 * b.y + b2 * c.y;
    o.z = b0 * a.z + b1 * b.z + b2 * c.z;
    o.w = b0 * a.w + b1 * b.w + b2 * c.w;
    out[i] = o;
  }
}

extern "C" void kernel_launch(void* const* d_in, const int* in_sizes, int n_in,
                              void* d_out, int out_size, void* d_ws, size_t ws_size,
                              hipStream_t stream) {
  const float* target  = (const float*)d_in[0];
  const float* h0      = (const float*)d_in[1];
  const float* h1      = (const float*)d_in[2];
  const float* h2      = (const float*)d_in[3];
  const float* rf0     = (const float*)d_in[4];
  const float* rf1     = (const float*)d_in[5];
  const float* rf2     = (const float*)d_in[6];
  const int*   nei0    = (const int*)d_in[7];
  const int*   nei1    = (const int*)d_in[8];
  const float* att0    = (const float*)d_in[9];
  const float* att2_0  = (const float*)d_in[10];
  const float* Wr0     = (const float*)d_in[11];
  const float* br0     = (const float*)d_in[12];
  const float* Wr2_0   = (const float*)d_in[13];
  const float* br2_0   = (const float*)d_in[14];
  const float* aggW0   = (const float*)d_in[15];
  const float* aggb0   = (const float*)d_in[16];
  const float* aggatt0 = (const float*)d_in[17];
  const float* att1    = (const float*)d_in[18];
  const float* att2_1  = (const float*)d_in[19];
  const float* Wr1     = (const float*)d_in[20];
  const float* br1     = (const float*)d_in[21];
  const float* Wr2_1   = (const float*)d_in[22];
  const float* br2_1   = (const float*)d_in[23];
  const float* aggW1   = (const float*)d_in[24];
  const float* aggb1   = (const float*)d_in[25];
  const float* aggatt1 = (const float*)d_in[26];
  const float* interW  = (const float*)d_in[27];
  const float* interb  = (const float*)d_in[28];
  const float* interatt= (const float*)d_in[29];

  float* ws = (float*)d_ws;
  // ws layout (floats): [0..63] sumA0, [64..127] sumR0, [128..191] sumA1,
  // [192..255] sumR1, [256..319] Se0, [320..383] Se1, [384..447] St,
  // [448..451] intra betas, [456..458] final betas, [1024..) e-arrays.
  float* sums   = ws;
  float* Se0    = ws + 256;
  float* Se1    = ws + 320;
  float* St     = ws + 384;
  float* ibetas = ws + 448;
  float* fbetas = ws + 456;
  size_t EL = (size_t)NN * D;
  float* eA0 = ws + 1024;
  float* eR0 = eA0 + EL;
  float* eA1 = eR0 + EL;
  float* eR1 = eA1 + EL;

  k_zero<<<2, 256, 0, stream>>>(ws);
  k_relation<<<768, 256, 0, stream>>>(nei0, h1, rf1, h0, rf0, att0, att2_0,
                                      Wr0, br0, Wr2_0, br2_0, aggW0, aggb0,
                                      eA0, eR0, sums + 0, sums + 64);
  k_relation<<<768, 256, 0, stream>>>(nei1, h2, rf2, h0, rf0, att1, att2_1,
                                      Wr1, br1, Wr2_1, br2_1, aggW1, aggb1,
                                      eA1, eR1, sums + 128, sums + 192);
  k_intra_beta<<<1, 64, 0, stream>>>(sums, aggatt0, aggatt1, ibetas);
  k_mix<<<2048, 256, 0, stream>>>(eA0, eR0, eA1, eR1, target, interW, interb,
                                  ibetas, Se0, Se1, St);
  k_final_beta<<<1, 64, 0, stream>>>(Se0, interatt, fbetas);
  k_out<<<2048, 256, 0, stream>>>((const float4*)eA0, (const float4*)eA1,
                                  (const float4*)target, fbetas, (float4*)d_out);
}

// Round 2
// 1238.601 us; speedup vs baseline: 1.7068x; 1.7068x over previous
//
#include <hip/hip_runtime.h>
#include <math.h>

#define NN 100000
#define M1 200000
#define M2 100000

__device__ __forceinline__ float bc(float x, int l) {
  return __int_as_float(__builtin_amdgcn_readlane(__float_as_int(x), l));
}

__device__ __forceinline__ float wred(float x) {
  x += __shfl_xor(x, 1, 64);
  x += __shfl_xor(x, 2, 64);
  x += __shfl_xor(x, 4, 64);
  x += __shfl_xor(x, 8, 64);
  x += __shfl_xor(x, 16, 64);
  x += __shfl_xor(x, 32, 64);
  return x;
}

__global__ void k_zero(float* p) { p[blockIdx.x * 256 + threadIdx.x] = 0.f; }

// ---- A1: per-table-row (dot = att_hi . row, asum = ||row||_1) ----
__global__ void __launch_bounds__(256) k_tab_pairs(
    const float* __restrict__ tab, const float* __restrict__ atth,
    float2* __restrict__ out, int M) {
  int r = blockIdx.x * 256 + threadIdx.x;
  int stride = gridDim.x * 256;
  for (; r < M; r += stride) {
    const float4* row = (const float4*)(tab + (size_t)r * 64);
    float dot = 0.f, asum = 0.f;
#pragma unroll
    for (int k = 0; k < 16; k++) {
      float4 v = row[k];
      float4 a = *(const float4*)(atth + 4 * k);  // uniform -> s_load
      dot = fmaf(v.x, a.x, dot); dot = fmaf(v.y, a.y, dot);
      dot = fmaf(v.z, a.z, dot); dot = fmaf(v.w, a.w, dot);
      asum += fabsf(v.x) + fabsf(v.y) + fabsf(v.z) + fabsf(v.w);
    }
    out[r] = make_float2(dot, asum);
  }
}

// ---- A2: per-node (dot = att_lo . (W@x+b), asum = ||W@x+b||_1), W via SGPR stream ----
__device__ __forceinline__ float2 mvred(const float x[64], const float* __restrict__ W,
                                        const float* __restrict__ b,
                                        const float* __restrict__ att) {
  float dot = 0.f, asum = 0.f;
  for (int d = 0; d < 64; d++) {      // rolled; W[d*...] uniform -> scalar loads
    float r = b[d];
#pragma unroll
    for (int k4 = 0; k4 < 16; k4++) {
      float4 w = *(const float4*)(W + d * 64 + 4 * k4);
      r = fmaf(w.x, x[4 * k4 + 0], r);
      r = fmaf(w.y, x[4 * k4 + 1], r);
      r = fmaf(w.z, x[4 * k4 + 2], r);
      r = fmaf(w.w, x[4 * k4 + 3], r);
    }
    dot = fmaf(att[d], r, dot);
    asum += fabsf(r);
  }
  return make_float2(dot, asum);
}

__global__ void __launch_bounds__(256) k_node_pairs(
    const float* __restrict__ h0, const float* __restrict__ rf0,
    const float* __restrict__ Wa0, const float* __restrict__ ba0, const float* __restrict__ aa0,
    const float* __restrict__ Wa1, const float* __restrict__ ba1, const float* __restrict__ aa1,
    const float* __restrict__ Wq0, const float* __restrict__ bq0, const float* __restrict__ aq0,
    const float* __restrict__ Wq1, const float* __restrict__ bq1, const float* __restrict__ aq1,
    float2* __restrict__ np0a, float2* __restrict__ np1a,
    float2* __restrict__ np0r, float2* __restrict__ np1r) {
  int n = blockIdx.x * 256 + threadIdx.x;
  if (n >= NN) return;
  float x[64];
  const float4* row = (const float4*)(h0 + (size_t)n * 64);
#pragma unroll
  for (int k = 0; k < 16; k++) {
    float4 v = row[k];
    x[4 * k] = v.x; x[4 * k + 1] = v.y; x[4 * k + 2] = v.z; x[4 * k + 3] = v.w;
  }
  np0a[n] = mvred(x, Wa0, ba0, aa0);
  np1a[n] = mvred(x, Wa1, ba1, aa1);
  row = (const float4*)(rf0 + (size_t)n * 64);
#pragma unroll
  for (int k = 0; k < 16; k++) {
    float4 v = row[k];
    x[4 * k] = v.x; x[4 * k + 1] = v.y; x[4 * k + 2] = v.z; x[4 * k + 3] = v.w;
  }
  np0r[n] = mvred(x, Wq0, bq0, aq0);
  np1r[n] = mvred(x, Wq1, bq1, aq1);
}

// ---- B: attend. wave = node, lane = dim. Scores on lanes 0..15, gathers coalesced. ----
__global__ void __launch_bounds__(256) k_attend(
    const int* __restrict__ nei,
    const float* __restrict__ tabA, const float* __restrict__ tabR,
    const float2* __restrict__ tpA, const float2* __restrict__ tpR,
    const float2* __restrict__ npA, const float2* __restrict__ npR,
    float* __restrict__ outA, float* __restrict__ outR) {
  int lane = threadIdx.x & 63, wid = threadIdx.x >> 6;
  for (int n = blockIdx.x * 4 + wid; n < NN; n += gridDim.x * 4) {
    const int* nb = nei + (size_t)n * 8;
    int myidx = nb[lane & 7];
    float2 pnA = npA[n], pnR = npR[n];           // uniform
    float2 pn = (lane & 8) ? pnR : pnA;
    const float2* tpp = (lane & 8) ? tpR : tpA;
    float2 tp = tpp[myidx];
    float t = (pn.x + tp.x) / fmaxf(pn.y + tp.y, 1e-12f);
    t = (t >= 0.f) ? t : 0.01f * t;              // leaky_relu(0.01)
    float m = t;
    m = fmaxf(m, __shfl_xor(m, 1, 64));
    m = fmaxf(m, __shfl_xor(m, 2, 64));
    m = fmaxf(m, __shfl_xor(m, 4, 64));
    float u = expf(t - m);
    float den = u;
    den += __shfl_xor(den, 1, 64);
    den += __shfl_xor(den, 2, 64);
    den += __shfl_xor(den, 4, 64);
    float w = u / den;                           // lanes 0..7: branch A, 8..15: branch R
    int is[8];
#pragma unroll
    for (int s = 0; s < 8; s++) is[s] = nb[s];   // uniform -> s_load
    float vA[8], vR[8];
#pragma unroll
    for (int s = 0; s < 8; s++) {
      vA[s] = tabA[(size_t)is[s] * 64 + lane];
      vR[s] = tabR[(size_t)is[s] * 64 + lane];
    }
    float eA = 0.f, eR = 0.f;
#pragma unroll
    for (int s = 0; s < 8; s++) {
      eA = fmaf(bc(w, s), vA[s], eA);
      eR = fmaf(bc(w, 8 + s), vR[s], eR);
    }
    outA[(size_t)n * 64 + lane] = eA;
    outR[(size_t)n * 64 + lane] = eR;
  }
}

// ---- C: out[d] += sum_n tanh( W[d,:] . E[n,:] + b[d] ), lane = node ----
__global__ void __launch_bounds__(256) k_colsum(
    const float* __restrict__ E, const float* __restrict__ W,
    const float* __restrict__ bias, float* __restrict__ out) {
  int n = blockIdx.x * 256 + threadIdx.x;
  int lane = threadIdx.x & 63;
  bool valid = n < NN;
  float x[64];
  const float4* row = (const float4*)(E + (size_t)(valid ? n : 0) * 64);
#pragma unroll
  for (int k = 0; k < 16; k++) {
    float4 v = row[k];
    x[4 * k] = v.x; x[4 * k + 1] = v.y; x[4 * k + 2] = v.z; x[4 * k + 3] = v.w;
  }
  float keep = 0.f;
  for (int d = 0; d < 64; d++) {
    float r = bias[d];
#pragma unroll
    for (int k4 = 0; k4 < 16; k4++) {
      float4 w = *(const float4*)(W + d * 64 + 4 * k4);
      r = fmaf(w.x, x[4 * k4 + 0], r);
      r = fmaf(w.y, x[4 * k4 + 1], r);
      r = fmaf(w.z, x[4 * k4 + 2], r);
      r = fmaf(w.w, x[4 * k4 + 3], r);
    }
    float t = valid ? tanhf(r) : 0.f;
    t = wred(t);
    if (lane == d) keep = t;
  }
  atomicAdd(&out[lane], keep);
}

__global__ void k_ibeta(const float* __restrict__ sums,
                        const float* __restrict__ aggatt0,
                        const float* __restrict__ aggatt1,
                        float* __restrict__ betas) {
  int lane = threadIdx.x;  // 64 threads
  float invN = 1.f / (float)NN;
#pragma unroll
  for (int r = 0; r < 2; r++) {
    const float* aggatt = r ? aggatt1 : aggatt0;
    float ga = wred(aggatt[lane] * sums[r * 128 + lane] * invN);
    float gb = wred(aggatt[lane] * sums[r * 128 + 64 + lane] * invN);
    float mm = fmaxf(ga, gb);
    float ea = expf(ga - mm), eb = expf(gb - mm);
    if (lane == 0) {
      betas[2 * r] = ea / (ea + eb);
      betas[2 * r + 1] = eb / (ea + eb);
    }
  }
}

__global__ void __launch_bounds__(256) k_mix_elem(
    float4* __restrict__ pA0, const float4* __restrict__ pR0,
    float4* __restrict__ pA1, const float4* __restrict__ pR1,
    const float* __restrict__ betas) {
  float ba0 = betas[0], bb0 = betas[1], ba1 = betas[2], bb1 = betas[3];
  int total = NN * 64 / 4;
  for (int i = blockIdx.x * blockDim.x + threadIdx.x; i < total; i += gridDim.x * blockDim.x) {
    float4 a = pA0[i], b = pR0[i];
    float4 o;
    o.x = ba0 * a.x + bb0 * b.x; o.y = ba0 * a.y + bb0 * b.y;
    o.z = ba0 * a.z + bb0 * b.z; o.w = ba0 * a.w + bb0 * b.w;
    o.x = (o.x > 0.f) ? o.x : expm1f(o.x);
    o.y = (o.y > 0.f) ? o.y : expm1f(o.y);
    o.z = (o.z > 0.f) ? o.z : expm1f(o.z);
    o.w = (o.w > 0.f) ? o.w : expm1f(o.w);
    pA0[i] = o;
    a = pA1[i]; b = pR1[i];
    o.x = ba1 * a.x + bb1 * b.x; o.y = ba1 * a.y + bb1 * b.y;
    o.z = ba1 * a.z + bb1 * b.z; o.w = ba1 * a.w + bb1 * b.w;
    o.x = (o.x > 0.f) ? o.x : expm1f(o.x);
    o.y = (o.y > 0.f) ? o.y : expm1f(o.y);
    o.z = (o.z > 0.f) ? o.z : expm1f(o.z);
    o.w = (o.w > 0.f) ? o.w : expm1f(o.w);
    pA1[i] = o;
  }
}

__global__ void k_fbeta(const float* __restrict__ Ssum,
                        const float* __restrict__ interatt,
                        float* __restrict__ fbetas) {
  int lane = threadIdx.x;  // 64 threads
  float invN = 1.f / (float)NN;
  float ia = interatt[lane];
  float d0 = wred(ia * Ssum[lane] * invN);
  float d1 = wred(ia * Ssum[64 + lane] * invN);
  float d2 = wred(ia * Ssum[128 + lane] * invN);
  float mm = fmaxf(fmaxf(d0, d1), d2);
  float e0 = expf(d0 - mm), e1 = expf(d1 - mm), e2 = expf(d2 - mm);
  float inv = 1.f / (e0 + e1 + e2);
  if (lane == 0) { fbetas[0] = e0 * inv; fbetas[1] = e1 * inv; fbetas[2] = e2 * inv; }
}

__global__ void __launch_bounds__(256) k_out(
    const float4* __restrict__ E0, const float4* __restrict__ E1,
    const float4* __restrict__ T, const float* __restrict__ fb,
    float4* __restrict__ out) {
  float b0 = fb[0], b1 = fb[1], b2 = fb[2];
  int total = NN * 64 / 4;
  for (int i = blockIdx.x * blockDim.x + threadIdx.x; i < total; i += gridDim.x * blockDim.x) {
    float4 a = E0[i], b = E1[i], c = T[i];
    float4 o;
    o.x = b0 * a.x + b1 * b.x + b2 * c.x;
    o.y = b0 * a.y + b1 * b.y + b2 * c.y;
    o.z = b0 * a.z + b1 * b.z + b2 * c.z;
    o.w = b0 * a.w + b1 * b.w + b2 * c.w;
    out[i] = o;
  }
}

extern "C" void kernel_launch(void* const* d_in, const int* in_sizes, int n_in,
                              void* d_out, int out_size, void* d_ws, size_t ws_size,
                              hipStream_t stream) {
  const float* target  = (const float*)d_in[0];
  const float* h0      = (const float*)d_in[1];
  const float* h1      = (const float*)d_in[2];
  const float* h2      = (const float*)d_in[3];
  const float* rf0     = (const float*)d_in[4];
  const float* rf1     = (const float*)d_in[5];
  const float* rf2     = (const float*)d_in[6];
  const int*   nei0    = (const int*)d_in[7];
  const int*   nei1    = (const int*)d_in[8];
  const float* att0    = (const float*)d_in[9];
  const float* att2_0  = (const float*)d_in[10];
  const float* Wr0     = (const float*)d_in[11];
  const float* br0     = (const float*)d_in[12];
  const float* Wr2_0   = (const float*)d_in[13];
  const float* br2_0   = (const float*)d_in[14];
  const float* aggW0   = (const float*)d_in[15];
  const float* aggb0   = (const float*)d_in[16];
  const float* aggatt0 = (const float*)d_in[17];
  const float* att1    = (const float*)d_in[18];
  const float* att2_1  = (const float*)d_in[19];
  const float* Wr1     = (const float*)d_in[20];
  const float* br1     = (const float*)d_in[21];
  const float* Wr2_1   = (const float*)d_in[22];
  const float* br2_1   = (const float*)d_in[23];
  const float* aggW1   = (const float*)d_in[24];
  const float* aggb1   = (const float*)d_in[25];
  const float* aggatt1 = (const float*)d_in[26];
  const float* interW  = (const float*)d_in[27];
  const float* interb  = (const float*)d_in[28];
  const float* interatt= (const float*)d_in[29];

  // ws: [0..447] atomic sums (s0A,s0R,s1A,s1R,S0,S1,S2), [448..451] ibetas,
  // [456..459] fbetas, [1024..) four e-arrays (proven-fit 102.5MB layout).
  float* ws = (float*)d_ws;
  float* sums   = ws;
  float* S012   = ws + 256;
  float* ibetas = ws + 448;
  float* fbetas = ws + 456;
  size_t EL = (size_t)NN * 64;
  float* eA0 = ws + 1024;
  float* eR0 = eA0 + EL;
  float* eA1 = eR0 + EL;
  float* eR1 = eA1 + EL;

  // scratch pairs live in d_out (8MB of 25.6MB; k_out rewrites all of d_out at the end)
  float* ob = (float*)d_out;
  float2* tp0a = (float2*)(ob);                 // M1 pairs = 400k floats
  float2* tp0r = (float2*)(ob + 400000);        // 400k
  float2* tp1a = (float2*)(ob + 800000);        // 200k
  float2* tp1r = (float2*)(ob + 1000000);       // 200k
  float2* np0a = (float2*)(ob + 1200000);       // 200k
  float2* np0r = (float2*)(ob + 1400000);
  float2* np1a = (float2*)(ob + 1600000);
  float2* np1r = (float2*)(ob + 1800000);       // ends at 2.0M floats

  k_zero<<<2, 256, 0, stream>>>(ws);
  k_tab_pairs<<<782, 256, 0, stream>>>(h1,  att0   + 64, tp0a, M1);
  k_tab_pairs<<<782, 256, 0, stream>>>(rf1, att2_0 + 64, tp0r, M1);
  k_tab_pairs<<<391, 256, 0, stream>>>(h2,  att1   + 64, tp1a, M2);
  k_tab_pairs<<<391, 256, 0, stream>>>(rf2, att2_1 + 64, tp1r, M2);
  k_node_pairs<<<391, 256, 0, stream>>>(h0, rf0,
      Wr0, br0, att0, Wr1, br1, att1,
      Wr2_0, br2_0, att2_0, Wr2_1, br2_1, att2_1,
      np0a, np1a, np0r, np1r);
  k_attend<<<2048, 256, 0, stream>>>(nei0, h1, rf1, tp0a, tp0r, np0a, np0r, eA0, eR0);
  k_attend<<<2048, 256, 0, stream>>>(nei1, h2, rf2, tp1a, tp1r, np1a, np1r, eA1, eR1);
  k_colsum<<<391, 256, 0, stream>>>(eA0, aggW0, aggb0, sums + 0);
  k_colsum<<<391, 256, 0, stream>>>(eR0, aggW0, aggb0, sums + 64);
  k_colsum<<<391, 256, 0, stream>>>(eA1, aggW1, aggb1, sums + 128);
  k_colsum<<<391, 256, 0, stream>>>(eR1, aggW1, aggb1, sums + 192);
  k_ibeta<<<1, 64, 0, stream>>>(sums, aggatt0, aggatt1, ibetas);
  k_mix_elem<<<2048, 256, 0, stream>>>((float4*)eA0, (const float4*)eR0,
                                       (float4*)eA1, (const float4*)eR1, ibetas);
  k_colsum<<<391, 256, 0, stream>>>(eA0, interW, interb, S012 + 0);
  k_colsum<<<391, 256, 0, stream>>>(eA1, interW, interb, S012 + 64);
  k_colsum<<<391, 256, 0, stream>>>(target, interW, interb, S012 + 128);
  k_fbeta<<<1, 64, 0, stream>>>(S012, interatt, fbetas);
  k_out<<<2048, 256, 0, stream>>>((const float4*)eA0, (const float4*)eA1,
                                  (const float4*)target, fbetas, (float4*)d_out);
}